// Round 22
// baseline (76.087 us; speedup 1.0000x reference)
//
#include <hip/hip_runtime.h>
#include <hip/hip_bf16.h>
#include <cstddef>
#include <cstdint>

#define BB 4
#define CC 256
#define II 32
#define NN 4096

// 1/sqrt(32) * log2(e): fold softmax scale AND exp->exp2 conversion into q.
#define SCALE_Q 0.25505572751402893f

typedef __attribute__((ext_vector_type(8))) short bf16x8;
typedef __attribute__((ext_vector_type(16))) float f32x16;

static __device__ __forceinline__ int cvt_pk_bf16(float lo, float hi) {
  int d;
  asm("v_cvt_pk_bf16_f32 %0, %1, %2" : "=v"(d) : "v"(lo), "v"(hi));
  return d;
}
static __device__ __forceinline__ void perm32swap_f(float& a, float& b) {
  asm("v_permlane32_swap_b32 %0, %1" : "+v"(a), "+v"(b));
}
static __device__ __forceinline__ float max3f(float a, float b, float c) {
  float d;
  asm("v_max3_f32 %0, %1, %2, %3" : "=v"(d) : "v"(a), "v"(b), "v"(c));
  return d;
}
static __device__ __forceinline__ f32x16 zero16() {
  f32x16 z;
#pragma unroll
  for (int i = 0; i < 16; ++i) z[i] = 0.0f;
  return z;
}
static __device__ __forceinline__ bf16x8 pack8(float f0, float f1, float f2,
    float f3, float f4, float f5, float f6, float f7) {
  union { int w[4]; bf16x8 v8; } u;
  u.w[0] = cvt_pk_bf16(f0, f1);
  u.w[1] = cvt_pk_bf16(f2, f3);
  u.w[2] = cvt_pk_bf16(f4, f5);
  u.w[3] = cvt_pk_bf16(f6, f7);
  return u.v8;
}
static __device__ __forceinline__ ushort f2bfu(float f) {
  union { __hip_bfloat16 h; ushort u; } cv;
  cv.h = __float2bfloat16(f);
  return cv.u;
}
static __device__ __forceinline__ int pack4_fp8(float a, float b, float c, float d) {
  int r = __builtin_amdgcn_cvt_pk_fp8_f32(a, b, 0, false);
  r = __builtin_amdgcn_cvt_pk_fp8_f32(c, d, r, true);
  return r;
}
static __device__ __forceinline__ unsigned char f2fp8(float f) {
  return (unsigned char)(__builtin_amdgcn_cvt_pk_fp8_f32(f, f, 0, false) & 0xff);
}

// Layouts:
//  qT/kT (bf16): [b][mt=n/32][frag=i/16][p]; p = 256*((i>>3)&1) + 8*(n&31) + (i&7)
//  vT8  (fp8):   [b][ct=c/32][nt=n/16][p];  p = 256*((n>>3)&1) + 8*(c&31) + (n&7)
//  wpre (bf16):  [g][ks][lane*8+j]; g: 0=Wq, 1=Wk, 2..9=Wv rows (g-2)*32..

// ---- W prepack (run once) --------------------------------------------------
__global__ __launch_bounds__(64) void prepack_w(
    const float* __restrict__ Wq, const float* __restrict__ Wk,
    const float* __restrict__ Wv, ushort* __restrict__ wpre) {
  const int g = blockIdx.x;   // 0..9
  const int ks = blockIdx.y;  // 0..15
  const int lane = threadIdx.x;
  const int l31 = lane & 31;
  const int h = lane >> 5;
  const float* src = (g == 0) ? (Wq + (size_t)l31 * CC)
                   : (g == 1) ? (Wk + (size_t)l31 * CC)
                              : (Wv + (size_t)((g - 2) * 32 + l31) * CC);
  const int c = ks * 16 + h * 8;
  const float4 a = *(const float4*)(src + c);
  const float4 b = *(const float4*)(src + c + 4);
  union { ushort us[8]; int4 i4; } pk;
  pk.us[0] = f2bfu(a.x); pk.us[1] = f2bfu(a.y);
  pk.us[2] = f2bfu(a.z); pk.us[3] = f2bfu(a.w);
  pk.us[4] = f2bfu(b.x); pk.us[5] = f2bfu(b.y);
  pk.us[6] = f2bfu(b.z); pk.us[7] = f2bfu(b.w);
  *(int4*)(wpre + ((size_t)g * 16 + ks) * 512 + lane * 8) = pk.i4;
}

// ---- fused qkv projection, LDS-staged x + prepacked W (r18, unchanged) -----
__global__ __launch_bounds__(320, 2) void proj_lds(
    const float* __restrict__ bq, const float* __restrict__ bk,
    const float* __restrict__ bv, const float* __restrict__ x,
    const ushort* __restrict__ wpre,
    ushort* __restrict__ qT, ushort* __restrict__ kT,
    unsigned char* __restrict__ vT8) {
  __shared__ float xs[256 * 32];

  const int tid = threadIdx.x;
  const int w = tid >> 6;
  const int lane = tid & 63;
  const int l31 = lane & 31;
  const int h = lane >> 5;
  const int b = blockIdx.x;
  const int n0 = blockIdx.y * 32;

  {
    const float* xb = x + (size_t)b * CC * NN + n0;
    for (int i = w; i < 32; i += 5) {
      const float* src = xb + (size_t)(i * 8 + (lane >> 3)) * NN + (lane & 7) * 4;
      const float4 v = *(const float4*)src;
      *(float4*)&xs[i * 256 + lane * 4] = v;
    }
  }
  __syncthreads();

  const ushort* wp0 = wpre + (size_t)((w == 0) ? 0 : (2 + (w - 1) * 2)) * 16 * 512 + lane * 8;
  const ushort* wp1 = wp0 + 16 * 512;

  f32x16 acc0 = zero16(), acc1 = zero16();
#pragma unroll 4
  for (int ks = 0; ks < 16; ++ks) {
    const int c = ks * 16 + h * 8;
    const float* xp = &xs[c * 32 + l31];
    bf16x8 xf = pack8(xp[0], xp[32], xp[64], xp[96],
                      xp[128], xp[160], xp[192], xp[224]);
    const bf16x8 wf0 = *reinterpret_cast<const bf16x8*>(wp0 + ks * 512);
    const bf16x8 wf1 = *reinterpret_cast<const bf16x8*>(wp1 + ks * 512);
    acc0 = __builtin_amdgcn_mfma_f32_32x32x16_bf16(wf0, xf, acc0, 0, 0, 0);
    acc1 = __builtin_amdgcn_mfma_f32_32x32x16_bf16(wf1, xf, acc1, 0, 0, 0);
  }

  if (w == 0) {
    ushort* qb = qT + (size_t)(b * 128 + (n0 >> 5)) * 1024;
    ushort* kb = kT + (size_t)(b * 128 + (n0 >> 5)) * 1024;
#pragma unroll
    for (int r = 0; r < 16; ++r) {
      const int i = (r & 3) + 8 * (r >> 2) + 4 * h;
      const size_t off = (size_t)(i >> 4) * 512 + ((i >> 3) & 1) * 256 + 8 * l31 + (i & 7);
      qb[off] = f2bfu((acc0[r] + bq[i]) * SCALE_Q);
      kb[off] = f2bfu(acc1[r] + bk[i]);
    }
  } else {
    const int n = n0 + l31;
    const size_t nsub = (size_t)(n >> 4) * 512 + ((size_t)((n >> 3) & 1)) * 256 + (n & 7);
    const size_t bbase = (size_t)b * (1 << 20);
#pragma unroll
    for (int r = 0; r < 16; ++r) {
      const int rp = (r & 3) + 8 * (r >> 2) + 4 * h;
      const int c0 = (w - 1) * 64 + rp;
      const int c1 = c0 + 32;
      vT8[bbase + (size_t)(c0 >> 5) * 131072 + nsub + (c0 & 31) * 8] = f2fp8(acc0[r] + bv[c0]);
      vT8[bbase + (size_t)(c1 >> 5) * 131072 + nsub + (c1 & 31) * 8] = f2fp8(acc1[r] + bv[c1]);
    }
  }
}

// ---- flash attention: c-split 4-wave blocks, 8 independent blocks/CU -------
// grid 1024 = 512 q-tiles x 2 channel-halves; block 256 (4 waves).
// Per iter (128 keys): wave w computes S for key-tile it*4+w (r20-identical
// softmax), packs into pbuf; PV = 8 fp8 MFMA on its 32 channels (ch*128+w*32).
// S/softmax duplicated x2 across c-halves; V is partitioned (no duplication).
__global__ __launch_bounds__(256, 8) void flash_csplit(
    const ushort* __restrict__ qT, const ushort* __restrict__ kT,
    const unsigned char* __restrict__ vT8, const float* __restrict__ x,
    const float* __restrict__ gamma, float* __restrict__ out) {
  __shared__ __align__(16) unsigned char pbuf[32 * 136];  // P fp8 [q][key 0..127]
  __shared__ float mlds[132];  // per-wave rowmax [w*33 + q]
  __shared__ float slds[132];  // per-wave rowsum [w*33 + q]

  const int tid = threadIdx.x;
  const int lane = tid & 63;
  const int w = tid >> 6;      // 0..3
  const int q = lane & 31;
  const int h = lane >> 5;

  const int wg = blockIdx.x;
  const int xcd = wg & 7;
  const int pos = wg >> 3;            // 0..127
  const int b = xcd >> 1;
  const int nt = ((xcd & 1) << 6) + (pos & 63);
  const int ch = pos >> 6;            // channel half: 0 or 1
  const int n0 = nt * 32;

  const ushort* qb = qT + (size_t)(b * 128 + nt) * 1024 + lane * 8;
  const bf16x8 qf0 = *reinterpret_cast<const bf16x8*>(qb);
  const bf16x8 qf1 = *reinterpret_cast<const bf16x8*>(qb + 512);

  const ushort* ktb = kT + (size_t)b * 128 * 1024;
  // this wave's channel tile: ct = ch*4 + w
  const unsigned char* vtb = vT8 + ((size_t)b << 20) +
                             (size_t)(ch * 4 + w) * 131072 + lane * 8;

  f32x16 acc = zero16();
  float m_run = -1e30f, l_run = 0.0f;

  for (int it = 0; it < 32; ++it) {
    // ---- S phase: this wave's 32 keys (key-tile it*4 + w) ----
    const ushort* kc = ktb + (size_t)(it * 4 + w) * 1024 + lane * 8;
    const bf16x8 kf0 = *reinterpret_cast<const bf16x8*>(kc);
    const bf16x8 kf1 = *reinterpret_cast<const bf16x8*>(kc + 512);
    f32x16 st = zero16();
    __builtin_amdgcn_s_setprio(1);
    st = __builtin_amdgcn_mfma_f32_32x32x16_bf16(kf0, qf0, st, 0, 0, 0);
    st = __builtin_amdgcn_mfma_f32_32x32x16_bf16(kf1, qf1, st, 0, 0, 0);
    __builtin_amdgcn_s_setprio(0);

    // per-wave rowmax over its 32 keys
    float m0 = max3f(st[0], st[1], st[2]);
    float m1 = max3f(st[3], st[4], st[5]);
    float m2 = max3f(st[6], st[7], st[8]);
    float m3 = max3f(st[9], st[10], st[11]);
    m0 = max3f(st[12], st[13], m0);
    m1 = max3f(st[14], st[15], m1);
    float mx = max3f(m0, m1, fmaxf(m2, m3));
    float sw1 = mx, sw2 = mx;
    perm32swap_f(sw1, sw2);
    if (lane < 32) mlds[w * 33 + q] = fmaxf(sw1, sw2);
    __syncthreads();  // B1: rowmaxes visible; pbuf(it-1) fully consumed

    float tmax = mlds[q];
#pragma unroll
    for (int i = 1; i < 4; ++i) tmax = fmaxf(tmax, mlds[i * 33 + q]);

    if (__any(tmax > m_run + 8.0f)) {
      const float mnew = fmaxf(m_run, tmax);
      const float f = __builtin_amdgcn_exp2f(m_run - mnew);
#pragma unroll
      for (int r = 0; r < 16; ++r) acc[r] *= f;
      l_run *= f;
      m_run = mnew;
    }

#pragma unroll
    for (int r = 0; r < 16; ++r) st[r] = __builtin_amdgcn_exp2f(st[r] - m_run);
    float s0 = ((st[0] + st[1]) + (st[2] + st[3])) +
               ((st[4] + st[5]) + (st[6] + st[7]));
    float s1 = ((st[8] + st[9]) + (st[10] + st[11])) +
               ((st[12] + st[13]) + (st[14] + st[15]));
    float pssum = s0 + s1;
    float pa = pssum, pb = pssum;
    perm32swap_f(pa, pb);
    pssum = pa + pb;
    if (lane < 32) slds[w * 33 + q] = pssum;

    // pack P -> fp8 into pbuf[q][m_local]; m_local = w*32 + rg*8 + 4h + j
#pragma unroll
    for (int rg = 0; rg < 4; ++rg) {
      const int pk = pack4_fp8(st[rg * 4], st[rg * 4 + 1], st[rg * 4 + 2], st[rg * 4 + 3]);
      *reinterpret_cast<int*>(&pbuf[q * 136 + w * 32 + rg * 8 + h * 4]) = pk;
    }
    __syncthreads();  // B2: P + sums visible

    float tsum = slds[q];
#pragma unroll
    for (int i = 1; i < 4; ++i) tsum += slds[i * 33 + q];
    l_run += tsum;

    // ---- PV phase: 32 channels x 128 keys = 8 fp8 MFMA ----
    const unsigned char* vc = vtb + (size_t)(it * 8) * 512;
    __builtin_amdgcn_s_setprio(1);
#pragma unroll
    for (int kt = 0; kt < 8; ++kt) {
      const long vf = *reinterpret_cast<const long*>(vc + (size_t)kt * 512);
      const long pfr = *reinterpret_cast<const long*>(&pbuf[q * 136 + kt * 16 + h * 8]);
      acc = __builtin_amdgcn_mfma_f32_32x32x16_fp8_fp8(vf, pfr, acc, 0, 0, 0);
    }
    __builtin_amdgcn_s_setprio(0);
  }

  // ---- epilogue: out = gamma * O/l + x ----
  const float g = gamma[0];
  const float linv = 1.0f / l_run;
#pragma unroll
  for (int r = 0; r < 16; ++r) {
    const int c = ch * 128 + w * 32 + (r & 3) + 8 * (r >> 2) + 4 * h;
    const size_t idx = ((size_t)b * CC + c) * NN + n0 + q;
    out[idx] = g * acc[r] * linv + x[idx];
  }
}

extern "C" void kernel_launch(void* const* d_in, const int* in_sizes, int n_in,
                              void* d_out, int out_size, void* d_ws, size_t ws_size,
                              hipStream_t stream) {
  const float* x = (const float*)d_in[0];
  const float* Wq = (const float*)d_in[1];
  const float* bq = (const float*)d_in[2];
  const float* Wk = (const float*)d_in[3];
  const float* bk = (const float*)d_in[4];
  const float* Wv = (const float*)d_in[5];
  const float* bv = (const float*)d_in[6];
  const float* gamma = (const float*)d_in[7];
  float* out = (float*)d_out;

  ushort* qT = (ushort*)d_ws;                                   // 1 MB
  ushort* kT = qT + (size_t)524288;                             // 1 MB
  unsigned char* vT8 = (unsigned char*)(kT + (size_t)524288);   // 4 MB
  ushort* wpre = (ushort*)(vT8 + ((size_t)1 << 22));            // 160 KB

  prepack_w<<<dim3(10, 16), dim3(64), 0, stream>>>(Wq, Wk, Wv, wpre);
  proj_lds<<<dim3(BB, NN / 32), dim3(320), 0, stream>>>(
      bq, bk, bv, x, wpre, qT, kT, vT8);
  flash_csplit<<<dim3(1024), dim3(256), 0, stream>>>(
      qT, kT, vT8, x, gamma, out);
}

// Round 23
// 64.858 us; speedup vs baseline: 1.1731x; 1.1731x over previous
//
#include <hip/hip_runtime.h>
#include <hip/hip_bf16.h>
#include <cstddef>
#include <cstdint>

#define BB 4
#define CC 256
#define II 32
#define NN 4096

// 1/sqrt(32) * log2(e): fold softmax scale AND exp->exp2 conversion into q.
#define SCALE_Q 0.25505572751402893f

typedef __attribute__((ext_vector_type(8))) short bf16x8;
typedef __attribute__((ext_vector_type(16))) float f32x16;

static __device__ __forceinline__ int cvt_pk_bf16(float lo, float hi) {
  int d;
  asm("v_cvt_pk_bf16_f32 %0, %1, %2" : "=v"(d) : "v"(lo), "v"(hi));
  return d;
}
static __device__ __forceinline__ void perm32swap_f(float& a, float& b) {
  asm("v_permlane32_swap_b32 %0, %1" : "+v"(a), "+v"(b));
}
static __device__ __forceinline__ float max3f(float a, float b, float c) {
  float d;
  asm("v_max3_f32 %0, %1, %2, %3" : "=v"(d) : "v"(a), "v"(b), "v"(c));
  return d;
}
static __device__ __forceinline__ f32x16 zero16() {
  f32x16 z;
#pragma unroll
  for (int i = 0; i < 16; ++i) z[i] = 0.0f;
  return z;
}
// VGPR-form S-MFMA (keeps the softmax operand out of AGPRs).
static __device__ __forceinline__ void mfma_bf16_first(bf16x8 a, bf16x8 b, f32x16& c) {
  asm("s_nop 1\n\tv_mfma_f32_32x32x16_bf16 %0, %1, %2, %0"
      : "+v"(c) : "v"(a), "v"(b));
}
static __device__ __forceinline__ void mfma_bf16_last(bf16x8 a, bf16x8 b, f32x16& c) {
  asm("v_mfma_f32_32x32x16_bf16 %0, %1, %2, %0\n\ts_nop 7\n\ts_nop 7"
      : "+v"(c) : "v"(a), "v"(b));
}
static __device__ __forceinline__ bf16x8 pack8(float f0, float f1, float f2,
    float f3, float f4, float f5, float f6, float f7) {
  union { int w[4]; bf16x8 v8; } u;
  u.w[0] = cvt_pk_bf16(f0, f1);
  u.w[1] = cvt_pk_bf16(f2, f3);
  u.w[2] = cvt_pk_bf16(f4, f5);
  u.w[3] = cvt_pk_bf16(f6, f7);
  return u.v8;
}
static __device__ __forceinline__ ushort f2bfu(float f) {
  union { __hip_bfloat16 h; ushort u; } cv;
  cv.h = __float2bfloat16(f);
  return cv.u;
}
static __device__ __forceinline__ int pack4_fp8(float a, float b, float c, float d) {
  int r = __builtin_amdgcn_cvt_pk_fp8_f32(a, b, 0, false);
  r = __builtin_amdgcn_cvt_pk_fp8_f32(c, d, r, true);
  return r;
}
static __device__ __forceinline__ unsigned char f2fp8(float f) {
  return (unsigned char)(__builtin_amdgcn_cvt_pk_fp8_f32(f, f, 0, false) & 0xff);
}

// Layouts:
//  qT/kT (bf16): [b][mt=n/32][frag=i/16][p]; p = 256*((i>>3)&1) + 8*(n&31) + (i&7)
//  vT8  (fp8):   [b][ct=c/32][nt=n/16][p];  p = 256*((n>>3)&1) + 8*(c&31) + (n&7)
//  wpre (bf16):  [g][ks][lane*8+j]; g: 0=Wq, 1=Wk, 2..9=Wv rows (g-2)*32..

// ---- W prepack: fragment-layout bf16 copies of Wq/Wk/Wv (run once) ---------
__global__ __launch_bounds__(64) void prepack_w(
    const float* __restrict__ Wq, const float* __restrict__ Wk,
    const float* __restrict__ Wv, ushort* __restrict__ wpre) {
  const int g = blockIdx.x;   // 0..9
  const int ks = blockIdx.y;  // 0..15
  const int lane = threadIdx.x;
  const int l31 = lane & 31;
  const int h = lane >> 5;
  const float* src = (g == 0) ? (Wq + (size_t)l31 * CC)
                   : (g == 1) ? (Wk + (size_t)l31 * CC)
                              : (Wv + (size_t)((g - 2) * 32 + l31) * CC);
  const int c = ks * 16 + h * 8;
  const float4 a = *(const float4*)(src + c);
  const float4 b = *(const float4*)(src + c + 4);
  union { ushort us[8]; int4 i4; } pk;
  pk.us[0] = f2bfu(a.x); pk.us[1] = f2bfu(a.y);
  pk.us[2] = f2bfu(a.z); pk.us[3] = f2bfu(a.w);
  pk.us[4] = f2bfu(b.x); pk.us[5] = f2bfu(b.y);
  pk.us[6] = f2bfu(b.z); pk.us[7] = f2bfu(b.w);
  *(int4*)(wpre + ((size_t)g * 16 + ks) * 512 + lane * 8) = pk.i4;
}

// ---- fused qkv projection, LDS-staged x + prepacked W ----------------------
// grid (B, N/32), block 320. Block stages x[256][32] (32 KB) into LDS once;
// wave 0 computes q+k, waves 1..4 compute v. W fragments are contiguous 1KB
// wave-loads from wpre.
__global__ __launch_bounds__(320, 2) void proj_lds(
    const float* __restrict__ bq, const float* __restrict__ bk,
    const float* __restrict__ bv, const float* __restrict__ x,
    const ushort* __restrict__ wpre,
    ushort* __restrict__ qT, ushort* __restrict__ kT,
    unsigned char* __restrict__ vT8) {
  __shared__ float xs[256 * 32];  // [c][n] rows of 128 B

  const int tid = threadIdx.x;
  const int w = tid >> 6;       // 0..4 (wave id)
  const int lane = tid & 63;
  const int l31 = lane & 31;
  const int h = lane >> 5;
  const int b = blockIdx.x;
  const int n0 = blockIdx.y * 32;

  // ---- stage x slab: 32 chunks of 1 KB (8 rows each), wave-strided ----
  {
    const float* xb = x + (size_t)b * CC * NN + n0;
    for (int i = w; i < 32; i += 5) {
      const float* src = xb + (size_t)(i * 8 + (lane >> 3)) * NN + (lane & 7) * 4;
      const float4 v = *(const float4*)src;
      *(float4*)&xs[i * 256 + lane * 4] = v;
    }
  }
  __syncthreads();

  const ushort* wp0 = wpre + (size_t)((w == 0) ? 0 : (2 + (w - 1) * 2)) * 16 * 512 + lane * 8;
  const ushort* wp1 = wp0 + 16 * 512;

  f32x16 acc0 = zero16(), acc1 = zero16();
#pragma unroll 4
  for (int ks = 0; ks < 16; ++ks) {
    const int c = ks * 16 + h * 8;
    const float* xp = &xs[c * 32 + l31];
    bf16x8 xf = pack8(xp[0], xp[32], xp[64], xp[96],
                      xp[128], xp[160], xp[192], xp[224]);
    const bf16x8 wf0 = *reinterpret_cast<const bf16x8*>(wp0 + ks * 512);
    const bf16x8 wf1 = *reinterpret_cast<const bf16x8*>(wp1 + ks * 512);
    acc0 = __builtin_amdgcn_mfma_f32_32x32x16_bf16(wf0, xf, acc0, 0, 0, 0);
    acc1 = __builtin_amdgcn_mfma_f32_32x32x16_bf16(wf1, xf, acc1, 0, 0, 0);
  }

  if (w == 0) {
    ushort* qb = qT + (size_t)(b * 128 + (n0 >> 5)) * 1024;
    ushort* kb = kT + (size_t)(b * 128 + (n0 >> 5)) * 1024;
#pragma unroll
    for (int r = 0; r < 16; ++r) {
      const int i = (r & 3) + 8 * (r >> 2) + 4 * h;
      const size_t off = (size_t)(i >> 4) * 512 + ((i >> 3) & 1) * 256 + 8 * l31 + (i & 7);
      qb[off] = f2bfu((acc0[r] + bq[i]) * SCALE_Q);
      kb[off] = f2bfu(acc1[r] + bk[i]);
    }
  } else {
    const int n = n0 + l31;
    const size_t nsub = (size_t)(n >> 4) * 512 + ((size_t)((n >> 3) & 1)) * 256 + (n & 7);
    const size_t bbase = (size_t)b * (1 << 20);
#pragma unroll
    for (int r = 0; r < 16; ++r) {
      const int rp = (r & 3) + 8 * (r >> 2) + 4 * h;
      const int c0 = (w - 1) * 64 + rp;
      const int c1 = c0 + 32;
      vT8[bbase + (size_t)(c0 >> 5) * 131072 + nsub + (c0 & 31) * 8] = f2fp8(acc0[r] + bv[c0]);
      vT8[bbase + (size_t)(c1 >> 5) * 131072 + nsub + (c1 & 31) * 8] = f2fp8(acc1[r] + bv[c1]);
    }
  }
}

// ---- flash attention: 8-wave coop, V register double-buffer ----------------
// (r14 structure — best measured flash at 55.6 us)
__global__ __launch_bounds__(512, 4) void flash_coop(
    const ushort* __restrict__ qT, const ushort* __restrict__ kT,
    const unsigned char* __restrict__ vT8, const float* __restrict__ x,
    const float* __restrict__ gamma, float* __restrict__ out) {
  __shared__ __align__(16) unsigned char pbuf[2][32 * 264];  // P fp8 [q][m_local]
  __shared__ float mlds[264];  // per-wave rowmax  [w*33 + q]
  __shared__ float slds[264];  // per-wave rowsum  [w*33 + q]

  const int tid = threadIdx.x;
  const int lane = tid & 63;
  const int w = tid >> 6;
  const int q = lane & 31;
  const int h = lane >> 5;

  const int wg = blockIdx.x;
  const int xcd = wg & 7;
  const int b = xcd >> 1;
  const int nt = ((xcd & 1) << 6) + (wg >> 3);
  const int n0 = nt * 32;

  const ushort* qb = qT + (size_t)(b * 128 + nt) * 1024 + lane * 8;
  const bf16x8 qf0 = *reinterpret_cast<const bf16x8*>(qb);
  const bf16x8 qf1 = *reinterpret_cast<const bf16x8*>(qb + 512);

  const ushort* ktb = kT + (size_t)b * 128 * 1024;
  const unsigned char* vtb = vT8 + ((size_t)b << 20) + (size_t)w * 131072 + lane * 8;

  f32x16 accA = zero16(), accB = zero16();
  float m_run = -1e30f, l_run = 0.0f;
  long vregA[8], vregB[8];  // V double-buffer (static addresses, full-iter prefetch)

  // ---------------- prologue: tile 0 S + softmax -> pbuf[0] ----------------
  {
    const ushort* kc = ktb + (size_t)(0 * 8 + w) * 1024 + lane * 8;
    const bf16x8 kf0 = *reinterpret_cast<const bf16x8*>(kc);
    const bf16x8 kf1 = *reinterpret_cast<const bf16x8*>(kc + 512);
    f32x16 st = zero16();
    mfma_bf16_first(kf0, qf0, st);
    mfma_bf16_last(kf1, qf1, st);

    // V(0) prefetch (consumed by PV(0) in iter t=1)
#pragma unroll
    for (int kp = 0; kp < 8; ++kp) {
      vregA[kp] = *reinterpret_cast<const long*>(vtb + (2 * kp) * 512);
      vregB[kp] = *reinterpret_cast<const long*>(vtb + (2 * kp + 1) * 512);
    }

    float m0 = max3f(st[0], st[1], st[2]);
    float m1 = max3f(st[3], st[4], st[5]);
    float m2 = max3f(st[6], st[7], st[8]);
    float m3 = max3f(st[9], st[10], st[11]);
    m0 = max3f(st[12], st[13], m0);
    m1 = max3f(st[14], st[15], m1);
    float mx = max3f(m0, m1, fmaxf(m2, m3));
    float sw1 = mx, sw2 = mx;
    perm32swap_f(sw1, sw2);
    if (lane < 32) mlds[w * 33 + q] = fmaxf(sw1, sw2);
    __syncthreads();
    float tmax = mlds[q];
#pragma unroll
    for (int i = 1; i < 8; ++i) tmax = fmaxf(tmax, mlds[i * 33 + q]);
    m_run = tmax;

#pragma unroll
    for (int r = 0; r < 16; ++r) st[r] = __builtin_amdgcn_exp2f(st[r] - m_run);
    float s0 = ((st[0] + st[1]) + (st[2] + st[3])) +
               ((st[4] + st[5]) + (st[6] + st[7]));
    float s1 = ((st[8] + st[9]) + (st[10] + st[11])) +
               ((st[12] + st[13]) + (st[14] + st[15]));
    float pssum = s0 + s1;
    float pa = pssum, pb = pssum;
    perm32swap_f(pa, pb);
    if (lane < 32) slds[w * 33 + q] = pa + pb;
#pragma unroll
    for (int rg = 0; rg < 4; ++rg) {
      const int pk = pack4_fp8(st[rg * 4], st[rg * 4 + 1], st[rg * 4 + 2], st[rg * 4 + 3]);
      *reinterpret_cast<int*>(&pbuf[0][q * 264 + w * 32 + rg * 8 + h * 4]) = pk;
    }
    __syncthreads();
    float tsum = slds[q];
#pragma unroll
    for (int i = 1; i < 8; ++i) tsum += slds[i * 33 + q];
    l_run = tsum;
  }

  // ---------------- main loop: t = 1..15 -----------------------------------
  for (int t = 1; t < 16; ++t) {
    const int pv = t - 1;           // PV consumes tile t-1
    const int pcur = pv & 1;
    const int pnext = t & 1;

    // K(t) loads issue here; consumed by S(t) AFTER PV — latency hidden
    const ushort* kc = ktb + (size_t)(t * 8 + w) * 1024 + lane * 8;
    const bf16x8 kf0 = *reinterpret_cast<const bf16x8*>(kc);
    const bf16x8 kf1 = *reinterpret_cast<const bf16x8*>(kc + 512);

    // PV(t-1): V from registers, pbuf reads software-pipelined (depth 1)
    const unsigned char* pb = &pbuf[pcur][q * 264 + h * 8];
    __builtin_amdgcn_s_setprio(1);
    long pA = *reinterpret_cast<const long*>(pb);
    long pB = *reinterpret_cast<const long*>(pb + 16);
#pragma unroll
    for (int kp = 0; kp < 8; ++kp) {
      long pAn = 0, pBn = 0;
      if (kp < 7) {
        pAn = *reinterpret_cast<const long*>(pb + (2 * kp + 2) * 16);
        pBn = *reinterpret_cast<const long*>(pb + (2 * kp + 3) * 16);
      }
      accA = __builtin_amdgcn_mfma_f32_32x32x16_fp8_fp8(vregA[kp], pA, accA, 0, 0, 0);
      accB = __builtin_amdgcn_mfma_f32_32x32x16_fp8_fp8(vregB[kp], pB, accB, 0, 0, 0);
      pA = pAn; pB = pBn;
    }

    // V(t) prefetch (consumed by PV(t) next iteration / epilogue)
    const unsigned char* vcn = vtb + (size_t)(t * 16) * 512;
#pragma unroll
    for (int kp = 0; kp < 8; ++kp) {
      vregA[kp] = *reinterpret_cast<const long*>(vcn + (2 * kp) * 512);
      vregB[kp] = *reinterpret_cast<const long*>(vcn + (2 * kp + 1) * 512);
    }

    // S(t) MFMA (K arrived during PV)
    f32x16 st = zero16();
    mfma_bf16_first(kf0, qf0, st);
    mfma_bf16_last(kf1, qf1, st);
    __builtin_amdgcn_s_setprio(0);

    // softmax(t)
    float m0 = max3f(st[0], st[1], st[2]);
    float m1 = max3f(st[3], st[4], st[5]);
    float m2 = max3f(st[6], st[7], st[8]);
    float m3 = max3f(st[9], st[10], st[11]);
    m0 = max3f(st[12], st[13], m0);
    m1 = max3f(st[14], st[15], m1);
    float mx = max3f(m0, m1, fmaxf(m2, m3));
    float sw1 = mx, sw2 = mx;
    perm32swap_f(sw1, sw2);
    if (lane < 32) mlds[w * 33 + q] = fmaxf(sw1, sw2);
    __syncthreads();  // B1: mlds(t) ready
    float tmax = mlds[q];
#pragma unroll
    for (int i = 1; i < 8; ++i) tmax = fmaxf(tmax, mlds[i * 33 + q]);

    if (__any(tmax > m_run + 8.0f)) {
      const float mnew = fmaxf(m_run, tmax);
      const float f = __builtin_amdgcn_exp2f(m_run - mnew);
#pragma unroll
      for (int r = 0; r < 16; ++r) { accA[r] *= f; accB[r] *= f; }
      l_run *= f;
      m_run = mnew;
    }

#pragma unroll
    for (int r = 0; r < 16; ++r) st[r] = __builtin_amdgcn_exp2f(st[r] - m_run);
    float s0 = ((st[0] + st[1]) + (st[2] + st[3])) +
               ((st[4] + st[5]) + (st[6] + st[7]));
    float s1 = ((st[8] + st[9]) + (st[10] + st[11])) +
               ((st[12] + st[13]) + (st[14] + st[15]));
    float pssum = s0 + s1;
    float pa = pssum, pb2 = pssum;
    perm32swap_f(pa, pb2);
    if (lane < 32) slds[w * 33 + q] = pa + pb2;

#pragma unroll
    for (int rg = 0; rg < 4; ++rg) {
      const int pk = pack4_fp8(st[rg * 4], st[rg * 4 + 1], st[rg * 4 + 2], st[rg * 4 + 3]);
      *reinterpret_cast<int*>(&pbuf[pnext][q * 264 + w * 32 + rg * 8 + h * 4]) = pk;
    }
    __syncthreads();  // B2: P(t) + sums visible

    float tsum = slds[q];
#pragma unroll
    for (int i = 1; i < 8; ++i) tsum += slds[i * 33 + q];
    l_run += tsum;
  }

  // ---------------- epilogue: PV(15) (V already in registers) --------------
  {
    const unsigned char* pb = &pbuf[1][q * 264 + h * 8];
    __builtin_amdgcn_s_setprio(1);
#pragma unroll
    for (int kp = 0; kp < 8; ++kp) {
      const long pA = *reinterpret_cast<const long*>(pb + (2 * kp) * 16);
      const long pB = *reinterpret_cast<const long*>(pb + (2 * kp + 1) * 16);
      accA = __builtin_amdgcn_mfma_f32_32x32x16_fp8_fp8(vregA[kp], pA, accA, 0, 0, 0);
      accB = __builtin_amdgcn_mfma_f32_32x32x16_fp8_fp8(vregB[kp], pB, accB, 0, 0, 0);
    }
    __builtin_amdgcn_s_setprio(0);
  }

  // ---- epilogue: out = gamma * O/l + x ----
  const float g = gamma[0];
  const float linv = 1.0f / l_run;
#pragma unroll
  for (int r = 0; r < 16; ++r) {
    const int c = w * 32 + (r & 3) + 8 * (r >> 2) + 4 * h;
    const size_t idx = ((size_t)b * CC + c) * NN + n0 + q;
    out[idx] = g * (accA[r] + accB[r]) * linv + x[idx];
  }
}

extern "C" void kernel_launch(void* const* d_in, const int* in_sizes, int n_in,
                              void* d_out, int out_size, void* d_ws, size_t ws_size,
                              hipStream_t stream) {
  const float* x = (const float*)d_in[0];
  const float* Wq = (const float*)d_in[1];
  const float* bq = (const float*)d_in[2];
  const float* Wk = (const float*)d_in[3];
  const float* bk = (const float*)d_in[4];
  const float* Wv = (const float*)d_in[5];
  const float* bv = (const float*)d_in[6];
  const float* gamma = (const float*)d_in[7];
  float* out = (float*)d_out;

  ushort* qT = (ushort*)d_ws;                          // B*128*1024 bf16
  ushort* kT = qT + (size_t)BB * 128 * 1024;           // B*128*1024 bf16
  unsigned char* vT8 = (unsigned char*)(kT + (size_t)BB * 128 * 1024);  // B*1MB fp8
  ushort* wpre = (ushort*)(vT8 + (size_t)BB * (1 << 20));  // 160 KB

  prepack_w<<<dim3(10, 16), dim3(64), 0, stream>>>(Wq, Wk, Wv, wpre);
  proj_lds<<<dim3(BB, NN / 32), dim3(320), 0, stream>>>(
      bq, bk, bv, x, wpre, qT, kT, vT8);
  flash_coop<<<dim3(512), dim3(512), 0, stream>>>(
      qT, kT, vT8, x, gamma, out);
}